// Round 1
// baseline (548.528 us; speedup 1.0000x reference)
//
#include <hip/hip_runtime.h>
#include <cstdint>

// Problem: B=4, S=2048, H=512, NH=8, HD=64
// out = OutProj( softmax( mask( (x Wq^T + bq)(x Wk^T + bk)^T / 8 ) ) (x Wv^T + bv) )
//
// Pipeline:
//  1) mask_bits_kernel: int32 mask -> u64 bitmask (2 MiB) via __ballot
//  2) gemm_bt<float,true> x3: Q/K/V projections, fp32 in -> bf16 head-split [B][NH][S][HD]
//     (Q scaled by 0.125 = 1/sqrt(HD), exact in bf16)
//  3) attn: flash-style online-softmax attention, bf16 MFMA 16x16x32, fp32 acc
//  4) gemm_bt<bf16(ushort),false>: output projection, bf16 in -> fp32 out + bias
//
// Workspace layout (needs 34 MiB):
//   [0,8Mi)   Qh bf16   [8Mi,16Mi) Kh   [16Mi,24Mi) Vh   [24Mi,32Mi) Oh   [32Mi,34Mi) mask bits

typedef __bf16 bf16x8 __attribute__((ext_vector_type(8)));
typedef float  f32x4  __attribute__((ext_vector_type(4)));

__device__ __forceinline__ ushort f2bf(float f) {
  union { float f; uint32_t u; } v; v.f = f;
  uint32_t u = v.u;
  return (ushort)((u + 0x7fffu + ((u >> 16) & 1u)) >> 16);
}

// ---------------------------------------------------------------- mask bits
__global__ __launch_bounds__(256) void mask_bits_kernel(
    const int* __restrict__ mask, unsigned long long* __restrict__ MB) {
  const int lane = threadIdx.x & 63;
  const int wid  = (int)((blockIdx.x * 256 + threadIdx.x) >> 6);  // 0..1023
  // 4*2048*32 = 262144 words total; 1024 waves -> 256 words each
  for (int j = 0; j < 256; ++j) {
    size_t word = (size_t)wid * 256 + j;
    int v = mask[word * 64 + lane];
    unsigned long long bal = __ballot(v != 0);
    if (lane == 0) MB[word] = bal;
  }
}

// ---------------------------------------------------------------- GEMM (bt)
// y[M=8192][N=512] = sum_k x[m][k] * W[n][k]; epilogue (acc + bias[n]) * scale
// HEAD_SPLIT: write bf16 to [B=4][NH=8][S=2048][HD=64]; else fp32 to [m][n].
template <bool IN_BF16, bool HEAD_SPLIT>
__global__ __launch_bounds__(256) void gemm_bt(
    const void* __restrict__ Xv, const float* __restrict__ W,
    const float* __restrict__ bias, void* __restrict__ Yv, float scale) {
  __shared__ ushort As[64][40];
  __shared__ ushort Ws[64][40];
  const int tid = threadIdx.x;
  const int wave = tid >> 6, lane = tid & 63;
  const int quad = lane >> 4, ln = lane & 15;
  const int m0 = blockIdx.x * 64, n0 = blockIdx.y * 64;
  f32x4 acc[4] = {};
  for (int kk = 0; kk < 512; kk += 32) {
    if constexpr (IN_BF16) {
      const ushort* X = (const ushort*)Xv;
      int row = tid >> 2, ch = tid & 3;  // 64 rows x 4 chunks of 8
      *(uint4*)&As[row][ch * 8] =
          *(const uint4*)(X + (size_t)(m0 + row) * 512 + kk + ch * 8);
    } else {
      const float* X = (const float*)Xv;
      for (int c = tid; c < 512; c += 256) {
        int row = c >> 3, ch = c & 7;
        float4 v = *(const float4*)(X + (size_t)(m0 + row) * 512 + kk + ch * 4);
        ushort4 o = { f2bf(v.x), f2bf(v.y), f2bf(v.z), f2bf(v.w) };
        *(ushort4*)&As[row][ch * 4] = o;
      }
    }
    for (int c = tid; c < 512; c += 256) {
      int row = c >> 3, ch = c & 7;
      float4 v = *(const float4*)(W + (size_t)(n0 + row) * 512 + kk + ch * 4);
      ushort4 o = { f2bf(v.x), f2bf(v.y), f2bf(v.z), f2bf(v.w) };
      *(ushort4*)&Ws[row][ch * 4] = o;
    }
    __syncthreads();
    bf16x8 a = *(const bf16x8*)&As[wave * 16 + ln][quad * 8];
#pragma unroll
    for (int nt = 0; nt < 4; ++nt) {
      bf16x8 bw = *(const bf16x8*)&Ws[nt * 16 + ln][quad * 8];
      acc[nt] = __builtin_amdgcn_mfma_f32_16x16x32_bf16(a, bw, acc[nt], 0, 0, 0);
    }
    __syncthreads();
  }
#pragma unroll
  for (int nt = 0; nt < 4; ++nt) {
    int n = n0 + nt * 16 + ln;
    float bv = bias[n];
#pragma unroll
    for (int r = 0; r < 4; ++r) {
      int m = m0 + wave * 16 + quad * 4 + r;
      float val = (acc[nt][r] + bv) * scale;
      if constexpr (HEAD_SPLIT) {
        int b = m >> 11, s = m & 2047;
        int h = n >> 6, hd = n & 63;
        ((ushort*)Yv)[(((size_t)(b * 8 + h) * 2048) + s) * 64 + hd] = f2bf(val);
      } else {
        ((float*)Yv)[(size_t)m * 512 + n] = val;
      }
    }
  }
}

// ---------------------------------------------------------------- attention
// grid (S/64=32, NH=8, B=4), 256 threads = 4 waves; wave owns 16 q-rows.
__global__ __launch_bounds__(256) void attn(
    const ushort* __restrict__ Q, const ushort* __restrict__ K,
    const ushort* __restrict__ V, const unsigned long long* __restrict__ MB,
    ushort* __restrict__ O) {
  __shared__ ushort Ks[64][72];        // [kv][hd]
  __shared__ ushort Vs[64][72];        // [hd][kv] (transposed at stage)
  __shared__ ushort Ps[4][16][72];     // per-wave P round-trip (C->A layout)
  const int tid = threadIdx.x;
  const int wave = tid >> 6, lane = tid & 63;
  const int quad = lane >> 4, ln = lane & 15;
  const int qt = blockIdx.x, h = blockIdx.y, b = blockIdx.z;
  const size_t headoff = (size_t)(b * 8 + h) * 2048 * 64;
  const ushort* Qp = Q + headoff + (size_t)(qt * 64) * 64;
  const ushort* Kp = K + headoff;
  const ushort* Vp = V + headoff;

  bf16x8 qf[2];
#pragma unroll
  for (int ks = 0; ks < 2; ++ks)
    qf[ks] = *(const bf16x8*)(Qp + (wave * 16 + ln) * 64 + ks * 32 + quad * 8);

  f32x4 po[4] = {};
  float m_i[4], l_i[4];
#pragma unroll
  for (int r = 0; r < 4; ++r) { m_i[r] = -3.0e38f; l_i[r] = 0.f; }
  const int sq_base = qt * 64 + wave * 16 + quad * 4;

  for (int it = 0; it < 32; ++it) {
    const int kv0 = it * 64;
    for (int c = tid; c < 512; c += 256) {     // stage K [kv][hd]
      int row = c >> 3, ch = c & 7;
      *(uint4*)&Ks[row][ch * 8] =
          *(const uint4*)(Kp + (size_t)(kv0 + row) * 64 + ch * 8);
    }
    for (int c = tid; c < 512; c += 256) {     // stage V transposed -> [hd][kv]
      int row = c >> 3, ch = c & 7;
      ushort tmp[8];
      *(uint4*)tmp = *(const uint4*)(Vp + (size_t)(kv0 + row) * 64 + ch * 8);
#pragma unroll
      for (int j = 0; j < 8; ++j) Vs[ch * 8 + j][row] = tmp[j];
    }
    unsigned long long mb[4];
#pragma unroll
    for (int r = 0; r < 4; ++r)
      mb[r] = MB[((size_t)b * 2048 + (sq_base + r)) * 32 + it];
    __syncthreads();

    f32x4 sa[4] = {};
#pragma unroll
    for (int ks = 0; ks < 2; ++ks) {
#pragma unroll
      for (int nt = 0; nt < 4; ++nt) {
        bf16x8 bb = *(const bf16x8*)&Ks[nt * 16 + ln][ks * 32 + quad * 8];
        sa[nt] = __builtin_amdgcn_mfma_f32_16x16x32_bf16(qf[ks], bb, sa[nt], 0, 0, 0);
      }
    }

#pragma unroll
    for (int r = 0; r < 4; ++r) {
      float rmax = -3.0e38f;
#pragma unroll
      for (int nt = 0; nt < 4; ++nt) {
        float s = sa[nt][r];
        if (!((mb[r] >> (nt * 16 + ln)) & 1ull)) s = -1.0e9f;
        sa[nt][r] = s;
        rmax = fmaxf(rmax, s);
      }
      rmax = fmaxf(rmax, __shfl_xor(rmax, 1, 16));
      rmax = fmaxf(rmax, __shfl_xor(rmax, 2, 16));
      rmax = fmaxf(rmax, __shfl_xor(rmax, 4, 16));
      rmax = fmaxf(rmax, __shfl_xor(rmax, 8, 16));
      float newm = fmaxf(m_i[r], rmax);
      float alpha = __expf(m_i[r] - newm);
      float rs = 0.f;
#pragma unroll
      for (int nt = 0; nt < 4; ++nt) {
        float p = __expf(sa[nt][r] - newm);
        rs += p;
        Ps[wave][quad * 4 + r][nt * 16 + ln] = f2bf(p);
      }
      rs += __shfl_xor(rs, 1, 16);
      rs += __shfl_xor(rs, 2, 16);
      rs += __shfl_xor(rs, 4, 16);
      rs += __shfl_xor(rs, 8, 16);
      l_i[r] = l_i[r] * alpha + rs;
      m_i[r] = newm;
      po[0][r] *= alpha; po[1][r] *= alpha; po[2][r] *= alpha; po[3][r] *= alpha;
    }

#pragma unroll
    for (int ks = 0; ks < 2; ++ks) {
      bf16x8 a = *(const bf16x8*)&Ps[wave][ln][ks * 32 + quad * 8];
#pragma unroll
      for (int nt = 0; nt < 4; ++nt) {
        bf16x8 bb = *(const bf16x8*)&Vs[nt * 16 + ln][ks * 32 + quad * 8];
        po[nt] = __builtin_amdgcn_mfma_f32_16x16x32_bf16(a, bb, po[nt], 0, 0, 0);
      }
    }
    __syncthreads();
  }

#pragma unroll
  for (int r = 0; r < 4; ++r) {
    float inv = 1.0f / l_i[r];
    int s = qt * 64 + wave * 16 + quad * 4 + r;
#pragma unroll
    for (int nt = 0; nt < 4; ++nt) {
      float val = po[nt][r] * inv;
      O[((size_t)(b * 2048) + s) * 512 + h * 64 + nt * 16 + ln] = f2bf(val);
    }
  }
}

// ---------------------------------------------------------------- launch
extern "C" void kernel_launch(void* const* d_in, const int* in_sizes, int n_in,
                              void* d_out, int out_size, void* d_ws, size_t ws_size,
                              hipStream_t stream) {
  const float* q    = (const float*)d_in[0];
  const float* k    = (const float*)d_in[1];
  const float* v    = (const float*)d_in[2];
  const int*   mask = (const int*)d_in[3];
  const float* Wq   = (const float*)d_in[4];
  const float* bq   = (const float*)d_in[5];
  const float* Wk   = (const float*)d_in[6];
  const float* bk   = (const float*)d_in[7];
  const float* Wv   = (const float*)d_in[8];
  const float* bv   = (const float*)d_in[9];
  const float* Wo   = (const float*)d_in[10];
  const float* bo   = (const float*)d_in[11];
  float* out = (float*)d_out;

  uint8_t* ws = (uint8_t*)d_ws;
  ushort* Qh = (ushort*)(ws + ((size_t)0 << 20));
  ushort* Kh = (ushort*)(ws + ((size_t)8 << 20));
  ushort* Vh = (ushort*)(ws + ((size_t)16 << 20));
  ushort* Oh = (ushort*)(ws + ((size_t)24 << 20));
  unsigned long long* MB = (unsigned long long*)(ws + ((size_t)32 << 20));

  mask_bits_kernel<<<256, 256, 0, stream>>>(mask, MB);
  gemm_bt<false, true><<<dim3(128, 8), 256, 0, stream>>>(q, Wq, bq, Qh, 0.125f);
  gemm_bt<false, true><<<dim3(128, 8), 256, 0, stream>>>(k, Wk, bk, Kh, 1.0f);
  gemm_bt<false, true><<<dim3(128, 8), 256, 0, stream>>>(v, Wv, bv, Vh, 1.0f);
  attn<<<dim3(32, 8, 4), 256, 0, stream>>>(Qh, Kh, Vh, MB, Oh);
  gemm_bt<true, false><<<dim3(128, 8), 256, 0, stream>>>(Oh, Wo, bo, out, 1.0f);
}

// Round 2
// 305.933 us; speedup vs baseline: 1.7930x; 1.7930x over previous
//
#include <hip/hip_runtime.h>
#include <cstdint>

// B=4, S=2048, H=512, NH=8, HD=64
// Pipeline (13 launches):
//   cvt Wq/Wk/Wv/Wo -> bf16 | mask -> u64 bits
//   [cvt q -> Ab ; gemm<0> -> Qh(*0.125)] [cvt k -> Ab ; gemm<0> -> Kh]
//   [cvt v -> Ab ; gemm<1> -> Vt transposed [b][h][hd][s]]
//   attn (S^T-form flash, kv-tile 128) -> Oh(=Ab)
//   gemm<2> Oh @ Wo^T + bo -> out (fp32)
// ws: Ab 0-8Mi | Qh 8-16 | Kh 16-24 | Vt 24-32 | MB 32-34 | Wb 34-36 MiB

typedef __bf16 bf16x8 __attribute__((ext_vector_type(8)));
typedef float  f32x4  __attribute__((ext_vector_type(4)));

#define MFMA16(a, b, c) __builtin_amdgcn_mfma_f32_16x16x32_bf16(a, b, c, 0, 0, 0)

__device__ __forceinline__ ushort f2bf(float f) {
  __bf16 h = (__bf16)f;
  union { __bf16 h; ushort u; } v; v.h = h;
  return v.u;
}

typedef const __attribute__((address_space(1))) unsigned int* gas_u32;
typedef __attribute__((address_space(3))) unsigned int* las_u32;
__device__ __forceinline__ void gll16(const void* g, void* l) {
  __builtin_amdgcn_global_load_lds((gas_u32)g, (las_u32)l, 16, 0, 0);
}

// ---------------------------------------------------------------- fp32 -> bf16
__global__ __launch_bounds__(256) void cvt_bf16(
    const float* __restrict__ src, ushort* __restrict__ dst, int n4) {
  int i = blockIdx.x * 256 + threadIdx.x;
  int stride = gridDim.x * 256;
  for (; i < n4; i += stride) {
    float4 v = ((const float4*)src)[i];
    ushort4 o = { f2bf(v.x), f2bf(v.y), f2bf(v.z), f2bf(v.w) };
    ((ushort4*)dst)[i] = o;
  }
}

// ---------------------------------------------------------------- mask bits
__global__ __launch_bounds__(256) void mask_bits_kernel(
    const int* __restrict__ mask, unsigned long long* __restrict__ MB) {
  const int lane = threadIdx.x & 63;
  const int wv = (int)((blockIdx.x * 256 + threadIdx.x) >> 6);  // 0..4095
  const size_t base = (size_t)wv * 64;                          // 64 words/wave
  for (int j = 0; j < 64; j += 4) {
    int v0 = mask[(base + j + 0) * 64 + lane];
    int v1 = mask[(base + j + 1) * 64 + lane];
    int v2 = mask[(base + j + 2) * 64 + lane];
    int v3 = mask[(base + j + 3) * 64 + lane];
    unsigned long long b0 = __ballot(v0 != 0), b1 = __ballot(v1 != 0);
    unsigned long long b2 = __ballot(v2 != 0), b3 = __ballot(v3 != 0);
    if (lane == 0) {
      MB[base + j] = b0; MB[base + j + 1] = b1;
      MB[base + j + 2] = b2; MB[base + j + 3] = b3;
    }
  }
}

// ---------------------------------------------------------------- GEMM bt (bf16)
// Y[M=8192][N=512] = X[m][k] * W[n][k] ; tile 64x128, BK=64, 256 thr, grid(128,4)
// EPI 0: bf16 head-split [b][h][s][hd], (acc+bias)*scale
// EPI 1: bf16 head-split transposed [b][h][hd][s]
// EPI 2: fp32 [m][512] + bias
template <int EPI>
__global__ __launch_bounds__(256) void gemm_bt(
    const ushort* __restrict__ X, const ushort* __restrict__ W,
    const float* __restrict__ bias, void* __restrict__ Y, float scale) {
  __shared__ ushort LDS[12288];           // As[64][64] | Ws[128][64]
  ushort* As = LDS;
  ushort* Ws = LDS + 4096;
  const int tid = threadIdx.x;
  const int wv = tid >> 6, l = tid & 63;
  const int quad = l >> 4, ln = l & 15;
  const int m0 = blockIdx.x * 64, n0 = blockIdx.y * 128;
  const int wm = (wv & 1) * 32, wn = (wv >> 1) * 64;
  const int sr = l >> 3, sc = l & 7;      // staging: 8 rows/instr, chunk=lane&7
  f32x4 acc[2][4] = {};
  for (int kk = 0; kk < 512; kk += 64) {
#pragma unroll
    for (int i = 0; i < 2; ++i) {        // A: 64 rows, 16/wave
      int row = wv * 16 + i * 8 + sr;
      gll16(X + (size_t)(m0 + row) * 512 + kk + ((sc ^ (row & 7)) * 8),
            As + (wv * 16 + i * 8) * 64);
    }
#pragma unroll
    for (int i = 0; i < 4; ++i) {        // B: 128 rows, 32/wave
      int row = wv * 32 + i * 8 + sr;
      gll16(W + (size_t)(n0 + row) * 512 + kk + ((sc ^ (row & 7)) * 8),
            Ws + (wv * 32 + i * 8) * 64);
    }
    __syncthreads();
#pragma unroll
    for (int ks = 0; ks < 2; ++ks) {
      bf16x8 a[2], bw[4];
#pragma unroll
      for (int mt = 0; mt < 2; ++mt) {
        int row = wm + mt * 16 + ln;
        a[mt] = *(const bf16x8*)&As[row * 64 + (((ks * 4 + quad) ^ (row & 7)) * 8)];
      }
#pragma unroll
      for (int nt = 0; nt < 4; ++nt) {
        int row = wn + nt * 16 + ln;
        bw[nt] = *(const bf16x8*)&Ws[row * 64 + (((ks * 4 + quad) ^ (row & 7)) * 8)];
      }
#pragma unroll
      for (int mt = 0; mt < 2; ++mt)
#pragma unroll
        for (int nt = 0; nt < 4; ++nt)
          acc[mt][nt] = MFMA16(a[mt], bw[nt], acc[mt][nt]);
    }
    __syncthreads();
  }
  float bval[4];
#pragma unroll
  for (int nt = 0; nt < 4; ++nt) bval[nt] = bias[n0 + wn + nt * 16 + ln];

  if constexpr (EPI == 1) {
    // transpose epilogue via LDS: T[128 n][64 m], xor-swizzled chunks
#pragma unroll
    for (int nt = 0; nt < 4; ++nt) {
      int row = wn + nt * 16 + ln;
#pragma unroll
      for (int mt = 0; mt < 2; ++mt) {
        int mbase = wm + mt * 16 + quad * 4;
        ushort4 pk;
        pk.x = f2bf((acc[mt][nt][0] + bval[nt]) * scale);
        pk.y = f2bf((acc[mt][nt][1] + bval[nt]) * scale);
        pk.z = f2bf((acc[mt][nt][2] + bval[nt]) * scale);
        pk.w = f2bf((acc[mt][nt][3] + bval[nt]) * scale);
        int col = ((mbase >> 3) ^ (row & 7)) * 8 + ((mbase >> 2) & 1) * 4;
        *(ushort4*)&LDS[row * 64 + col] = pk;
      }
    }
    __syncthreads();
#pragma unroll
    for (int i = 0; i < 4; ++i) {
      int c = tid + i * 256;              // 0..1023 : 128 rows x 8 chunks
      int row = c >> 3, cs = c & 7;
      int cl = cs ^ (row & 7);
      uint4 d = *(const uint4*)&LDS[row * 64 + cs * 8];
      int n = n0 + row, m = m0 + cl * 8;
      int bb = m >> 11, s = m & 2047, h = n >> 6, hd = n & 63;
      *(uint4*)((ushort*)Y + ((size_t)((bb * 8 + h) * 64 + hd)) * 2048 + s) = d;
    }
  } else {
#pragma unroll
    for (int nt = 0; nt < 4; ++nt) {
      int n = n0 + wn + nt * 16 + ln;
#pragma unroll
      for (int r = 0; r < 4; ++r) {
        int m = m0 + wm + ((nt * 0) /*keep*/) + 0;  // placeholder avoided below
        m = m0 + wm + (quad * 4 + r);
        // note: full m includes mt; handled in inner loop below
      }
    }
    // (explicit loops to keep indexing obvious)
#pragma unroll
    for (int mt = 0; mt < 2; ++mt) {
#pragma unroll
      for (int nt = 0; nt < 4; ++nt) {
        int n = n0 + wn + nt * 16 + ln;
#pragma unroll
        for (int r = 0; r < 4; ++r) {
          int m = m0 + wm + mt * 16 + quad * 4 + r;
          float val = (acc[mt][nt][r] + bval[nt]) * scale;
          if constexpr (EPI == 0) {
            int bb = m >> 11, s = m & 2047, h = n >> 6, hd = n & 63;
            ((ushort*)Y)[(((size_t)(bb * 8 + h) * 2048) + s) * 64 + hd] = f2bf(val);
          } else {
            ((float*)Y)[(size_t)m * 512 + n] = val;
          }
        }
      }
    }
  }
}

// ---------------------------------------------------------------- attention
// S^T-form flash: grid(bh=32, qb=32), 256 thr / 4 waves; wave owns 16 q (n-dim),
// kv-tile 128. Ks[kv][hd], Vs[hd][kv] xor-swizzled via global_load_lds.
__global__ __launch_bounds__(256) void attn(
    const ushort* __restrict__ Qh, const ushort* __restrict__ Kh,
    const ushort* __restrict__ Vt, const unsigned long long* __restrict__ MB,
    ushort* __restrict__ O) {
  __shared__ ushort Ks[128 * 64];
  __shared__ ushort Vs[64 * 128];
  __shared__ ushort Ps[4][16 * 136];      // per-wave P[q][kv], pad 8
  const int tid = threadIdx.x, wv = tid >> 6, l = tid & 63;
  const int quad = l >> 4, ln = l & 15;
  const int bh = blockIdx.x, qb = blockIdx.y;
  const int b = bh >> 3, h = bh & 7;
  const size_t hoff = (size_t)bh * 2048 * 64;
  const int q0 = qb * 64;
  const int qg = q0 + wv * 16 + ln;       // lane's q (softmax state owner)
  const int srK = l >> 3, scK = l & 7;    // K staging: 8 rows/instr
  const int srV = l >> 4, scV = l & 15;   // V staging: 4 rows/instr

  bf16x8 qf[2];
#pragma unroll
  for (int ks = 0; ks < 2; ++ks)
    qf[ks] = *(const bf16x8*)(Qh + hoff + (size_t)qg * 64 + ks * 32 + quad * 8);

  f32x4 po[4] = {};
  float m_i = -3.0e38f, l_i = 0.f;
  const unsigned long long* mrow = MB + ((size_t)b * 2048 + qg) * 32;

  for (int it = 0; it < 16; ++it) {
    const int kv0 = it * 128;
#pragma unroll
    for (int i = 0; i < 4; ++i) {
      int row = wv * 32 + i * 8 + srK;    // K rows (kv) 0..127
      gll16(Kh + hoff + (size_t)(kv0 + row) * 64 + ((scK ^ (row & 7)) * 8),
            Ks + (wv * 32 + i * 8) * 64);
      int rowv = wv * 16 + i * 4 + srV;   // V rows (hd) 0..63
      gll16(Vt + hoff + (size_t)rowv * 2048 + kv0 + ((scV ^ (rowv & 7)) * 8),
            Vs + (wv * 16 + i * 4) * 128);
    }
    unsigned long long mb0 = mrow[it * 2], mb1 = mrow[it * 2 + 1];
    __syncthreads();

    // S^T = K * Q^T : rows kv (C rows), cols q (C cols = ln)
    f32x4 sa[8];
#pragma unroll
    for (int mt = 0; mt < 8; ++mt) sa[mt] = (f32x4){0.f, 0.f, 0.f, 0.f};
#pragma unroll
    for (int ks = 0; ks < 2; ++ks) {
#pragma unroll
      for (int mt = 0; mt < 8; ++mt) {
        int row = mt * 16 + ln;
        bf16x8 ak = *(const bf16x8*)&Ks[row * 64 + (((ks * 4 + quad) ^ (row & 7)) * 8)];
        sa[mt] = MFMA16(ak, qf[ks], sa[mt]);
      }
    }
    // mask + tile max (per lane: q = ln, kv = mt*16+quad*4+r)
    float tm = -3.0e38f;
#pragma unroll
    for (int mt = 0; mt < 8; ++mt) {
      unsigned long long wsel = (mt < 4) ? mb0 : mb1;
      unsigned bits = (unsigned)(wsel >> ((mt * 16 + quad * 4) & 63)) & 0xFu;
#pragma unroll
      for (int r = 0; r < 4; ++r) {
        float s = ((bits >> r) & 1u) ? sa[mt][r] : -1.0e9f;
        sa[mt][r] = s;
        tm = fmaxf(tm, s);
      }
    }
    tm = fmaxf(tm, __shfl_xor(tm, 16));
    tm = fmaxf(tm, __shfl_xor(tm, 32));
    float newm = fmaxf(m_i, tm);
    float alpha = __expf(m_i - newm);
    float rs = 0.f;
#pragma unroll
    for (int mt = 0; mt < 8; ++mt) {
      float p0 = __expf(sa[mt][0] - newm);
      float p1 = __expf(sa[mt][1] - newm);
      float p2 = __expf(sa[mt][2] - newm);
      float p3 = __expf(sa[mt][3] - newm);
      rs += (p0 + p1) + (p2 + p3);
      ushort4 pk = { f2bf(p0), f2bf(p1), f2bf(p2), f2bf(p3) };
      *(ushort4*)&Ps[wv][ln * 136 + mt * 16 + quad * 4] = pk;
    }
    rs += __shfl_xor(rs, 16);
    rs += __shfl_xor(rs, 32);
    l_i = l_i * alpha + rs;
    m_i = newm;
#pragma unroll
    for (int r = 0; r < 4; ++r) {
      float ar = __shfl(alpha, (quad << 4) | (quad * 4 + r));
      po[0][r] *= ar; po[1][r] *= ar; po[2][r] *= ar; po[3][r] *= ar;
    }
    // PV: A = P[q][kv] (m=q=ln), B = Vs rows (n=hd)
#pragma unroll
    for (int ks = 0; ks < 4; ++ks) {
      bf16x8 ap = *(const bf16x8*)&Ps[wv][ln * 136 + ks * 32 + quad * 8];
#pragma unroll
      for (int ht = 0; ht < 4; ++ht) {
        int row = ht * 16 + ln;
        bf16x8 bv = *(const bf16x8*)&Vs[row * 128 + (((ks * 4 + quad) ^ (row & 7)) * 8)];
        po[ht] = MFMA16(ap, bv, po[ht]);
      }
    }
    __syncthreads();
  }

  float invl = 1.0f / l_i;                 // for q = ln
#pragma unroll
  for (int r = 0; r < 4; ++r) {
    float ir = __shfl(invl, (quad << 4) | (quad * 4 + r));
    int s = q0 + wv * 16 + quad * 4 + r;
#pragma unroll
    for (int ht = 0; ht < 4; ++ht)
      O[((size_t)(b * 2048 + s)) * 512 + h * 64 + ht * 16 + ln] =
          f2bf(po[ht][r] * ir);
  }
}

// ---------------------------------------------------------------- launch
extern "C" void kernel_launch(void* const* d_in, const int* in_sizes, int n_in,
                              void* d_out, int out_size, void* d_ws, size_t ws_size,
                              hipStream_t stream) {
  const float* q    = (const float*)d_in[0];
  const float* k    = (const float*)d_in[1];
  const float* v    = (const float*)d_in[2];
  const int*   mask = (const int*)d_in[3];
  const float* Wq   = (const float*)d_in[4];
  const float* bq   = (const float*)d_in[5];
  const float* Wk   = (const float*)d_in[6];
  const float* bk   = (const float*)d_in[7];
  const float* Wv   = (const float*)d_in[8];
  const float* bv   = (const float*)d_in[9];
  const float* Wo   = (const float*)d_in[10];
  const float* bo   = (const float*)d_in[11];
  float* out = (float*)d_out;

  uint8_t* ws = (uint8_t*)d_ws;
  const size_t MiB = 1u << 20;
  ushort* Ab = (ushort*)(ws + 0 * MiB);    // staging X / later Oh
  ushort* Qh = (ushort*)(ws + 8 * MiB);
  ushort* Kh = (ushort*)(ws + 16 * MiB);
  ushort* Vt = (ushort*)(ws + 24 * MiB);
  unsigned long long* MB = (unsigned long long*)(ws + 32 * MiB);
  ushort* WbQ = (ushort*)(ws + 34 * MiB);
  ushort* WbK = WbQ + 262144;
  ushort* WbV = WbK + 262144;
  ushort* WbO = WbV + 262144;

  cvt_bf16<<<256, 256, 0, stream>>>(Wq, WbQ, 65536);
  cvt_bf16<<<256, 256, 0, stream>>>(Wk, WbK, 65536);
  cvt_bf16<<<256, 256, 0, stream>>>(Wv, WbV, 65536);
  cvt_bf16<<<256, 256, 0, stream>>>(Wo, WbO, 65536);
  mask_bits_kernel<<<1024, 256, 0, stream>>>(mask, MB);

  cvt_bf16<<<1024, 256, 0, stream>>>(q, Ab, 1048576);
  gemm_bt<0><<<dim3(128, 4), 256, 0, stream>>>(Ab, WbQ, bq, Qh, 0.125f);
  cvt_bf16<<<1024, 256, 0, stream>>>(k, Ab, 1048576);
  gemm_bt<0><<<dim3(128, 4), 256, 0, stream>>>(Ab, WbK, bk, Kh, 1.0f);
  cvt_bf16<<<1024, 256, 0, stream>>>(v, Ab, 1048576);
  gemm_bt<1><<<dim3(128, 4), 256, 0, stream>>>(Ab, WbV, bv, Vt, 1.0f);

  attn<<<dim3(32, 32), 256, 0, stream>>>(Qh, Kh, Vt, MB, Ab);
  gemm_bt<2><<<dim3(128, 4), 256, 0, stream>>>(Ab, WbO, bo, out, 1.0f);
}

// Round 3
// 291.467 us; speedup vs baseline: 1.8820x; 1.0496x over previous
//
#include <hip/hip_runtime.h>
#include <cstdint>

// B=4, S=2048, H=512, NH=8, HD=64 — 5 launches:
//   cvt_w (Wq,Wk,Wv,Wo -> bf16 slab) | mask_bits (int32 -> u64)
//   qkv_gemm (fp32-staged, z selects q/k/v; Q folded scale 0.125*log2e; V transposed)
//   attn (no-max softmax: p = mask ? exp2(sa) : 0; l via ones-MFMA)
//   out_gemm (bf16 X @ Wo^T + bo -> fp32 out)
// ws: Ab 0-8Mi | Qh 8-16 | Kh 16-24 | Vt 24-32 | MB 32-34 | Wb 34-36 MiB

typedef __bf16 bf16x8 __attribute__((ext_vector_type(8)));
typedef float  f32x4  __attribute__((ext_vector_type(4)));

#define MFMA16(a, b, c) __builtin_amdgcn_mfma_f32_16x16x32_bf16(a, b, c, 0, 0, 0)

__device__ __forceinline__ ushort f2bf(float f) {
  union { __bf16 h; ushort u; } v; v.h = (__bf16)f; return v.u;
}

typedef const __attribute__((address_space(1))) unsigned int* gas_u32;
typedef __attribute__((address_space(3))) unsigned int* las_u32;
__device__ __forceinline__ void gll16(const void* g, void* l) {
  __builtin_amdgcn_global_load_lds((gas_u32)g, (las_u32)l, 16, 0, 0);
}

// ---------------------------------------------------------------- weights cvt
__global__ __launch_bounds__(256) void cvt_w(
    const float* __restrict__ w0, const float* __restrict__ w1,
    const float* __restrict__ w2, const float* __restrict__ w3,
    ushort* __restrict__ dst) {
  const float* src = (blockIdx.y == 0) ? w0 : (blockIdx.y == 1) ? w1
                   : (blockIdx.y == 2) ? w2 : w3;
  ushort* d = dst + (size_t)blockIdx.y * 262144;
  int i = blockIdx.x * 256 + threadIdx.x;
  for (int j = i; j < 65536; j += 16384) {
    float4 v = ((const float4*)src)[j];
    ushort4 o = { f2bf(v.x), f2bf(v.y), f2bf(v.z), f2bf(v.w) };
    ((ushort4*)d)[j] = o;
  }
}

// ---------------------------------------------------------------- mask bits
__global__ __launch_bounds__(256) void mask_bits_kernel(
    const int* __restrict__ mask, unsigned long long* __restrict__ MB) {
  const int lane = threadIdx.x & 63;
  const int wv = (int)((blockIdx.x * 256 + threadIdx.x) >> 6);
  const size_t base = (size_t)wv * 64;
  for (int j = 0; j < 64; j += 4) {
    int v0 = mask[(base + j + 0) * 64 + lane];
    int v1 = mask[(base + j + 1) * 64 + lane];
    int v2 = mask[(base + j + 2) * 64 + lane];
    int v3 = mask[(base + j + 3) * 64 + lane];
    unsigned long long b0 = __ballot(v0 != 0), b1 = __ballot(v1 != 0);
    unsigned long long b2 = __ballot(v2 != 0), b3 = __ballot(v3 != 0);
    if (lane == 0) {
      MB[base + j] = b0; MB[base + j + 1] = b1;
      MB[base + j + 2] = b2; MB[base + j + 3] = b3;
    }
  }
}

// ---------------------------------------------------------------- QKV GEMM
// Y[8192][512] = X f32 [m][k] * W bf16 [n][k]; tile 64x128, BK=64.
// z=0: Q, scale = 0.125*log2(e), EPI head-split; z=1: K; z=2: V transposed.
__global__ __launch_bounds__(256) void qkv_gemm(
    const float* __restrict__ q, const float* __restrict__ k,
    const float* __restrict__ v, const ushort* __restrict__ Wb,
    const float* __restrict__ bq, const float* __restrict__ bk,
    const float* __restrict__ bv, ushort* __restrict__ Qh,
    ushort* __restrict__ Kh, ushort* __restrict__ Vt) {
  __shared__ float  Asf[64 * 64];     // 16 KB fp32 A tile
  __shared__ ushort Ws[128 * 64];     // 16 KB bf16 W tile (reused as transpose buf)
  const int z = blockIdx.z;
  const float* X = (z == 0) ? q : (z == 1) ? k : v;
  const ushort* W = Wb + (size_t)z * 262144;
  const float* bias = (z == 0) ? bq : (z == 1) ? bk : bv;
  const float scale = (z == 0) ? 0.18033688011112042f : 1.0f;
  ushort* Y = (z == 0) ? Qh : (z == 1) ? Kh : Vt;

  const int tid = threadIdx.x, wv = tid >> 6, l = tid & 63;
  const int quad = l >> 4, ln = l & 15;
  const int m0 = blockIdx.x * 64, n0 = blockIdx.y * 128;
  const int wm = (wv & 1) * 32, wn = (wv >> 1) * 64;
  const int srA = l >> 4, sA = l & 15, cA = sA >> 1, hA = sA & 1;
  const int srW = l >> 3, scW = l & 7;
  f32x4 acc[2][4] = {};

  for (int kk = 0; kk < 512; kk += 64) {
#pragma unroll
    for (int i = 0; i < 4; ++i) {
      int rowa = wv * 16 + i * 4 + srA;   // fp32 A: 4 rows / instr
      gll16(X + (size_t)(m0 + rowa) * 512 + kk + ((cA ^ (rowa & 7)) * 8 + hA * 4),
            Asf + (wv * 16 + i * 4) * 64);
      int roww = wv * 32 + i * 8 + srW;   // bf16 W: 8 rows / instr
      gll16(W + (size_t)(n0 + roww) * 512 + kk + ((scW ^ (roww & 7)) * 8),
            Ws + (wv * 32 + i * 8) * 64);
    }
    __syncthreads();
#pragma unroll
    for (int ks = 0; ks < 2; ++ks) {
      bf16x8 a[2], bw[4];
#pragma unroll
      for (int mt = 0; mt < 2; ++mt) {
        int row = wm + mt * 16 + ln;
        int p = (ks * 4 + quad) ^ (row & 7);
        const float* ap = &Asf[row * 64 + p * 8];
        f32x4 x0 = *(const f32x4*)ap;
        f32x4 x1 = *(const f32x4*)(ap + 4);
        bf16x8 t;
#pragma unroll
        for (int j = 0; j < 4; ++j) { t[j] = (__bf16)x0[j]; t[4 + j] = (__bf16)x1[j]; }
        a[mt] = t;
      }
#pragma unroll
      for (int nt = 0; nt < 4; ++nt) {
        int row = wn + nt * 16 + ln;
        bw[nt] = *(const bf16x8*)&Ws[row * 64 + (((ks * 4 + quad) ^ (row & 7)) * 8)];
      }
#pragma unroll
      for (int mt = 0; mt < 2; ++mt)
#pragma unroll
        for (int nt = 0; nt < 4; ++nt)
          acc[mt][nt] = MFMA16(a[mt], bw[nt], acc[mt][nt]);
    }
    __syncthreads();
  }
  float bval[4];
#pragma unroll
  for (int nt = 0; nt < 4; ++nt) bval[nt] = bias[n0 + wn + nt * 16 + ln];

  if (z == 2) {  // transpose epilogue via Ws: T[128 n][64 m] xor-swizzled
#pragma unroll
    for (int nt = 0; nt < 4; ++nt) {
      int row = wn + nt * 16 + ln;
#pragma unroll
      for (int mt = 0; mt < 2; ++mt) {
        int mbase = wm + mt * 16 + quad * 4;
        ushort4 pk;
        pk.x = f2bf(acc[mt][nt][0] + bval[nt]);
        pk.y = f2bf(acc[mt][nt][1] + bval[nt]);
        pk.z = f2bf(acc[mt][nt][2] + bval[nt]);
        pk.w = f2bf(acc[mt][nt][3] + bval[nt]);
        int col = ((mbase >> 3) ^ (row & 7)) * 8 + ((mbase >> 2) & 1) * 4;
        *(ushort4*)&Ws[row * 64 + col] = pk;
      }
    }
    __syncthreads();
#pragma unroll
    for (int i = 0; i < 4; ++i) {
      int c = tid + i * 256;              // 128 rows x 8 chunks
      int row = c >> 3, cs = c & 7;
      int cl = cs ^ (row & 7);
      uint4 d = *(const uint4*)&Ws[row * 64 + cs * 8];
      int n = n0 + row, m = m0 + cl * 8;
      int bb = m >> 11, s = m & 2047, h = n >> 6, hd = n & 63;
      *(uint4*)(Y + ((size_t)((bb * 8 + h) * 64 + hd)) * 2048 + s) = d;
    }
  } else {
#pragma unroll
    for (int mt = 0; mt < 2; ++mt)
#pragma unroll
      for (int nt = 0; nt < 4; ++nt) {
        int n = n0 + wn + nt * 16 + ln;
#pragma unroll
        for (int r = 0; r < 4; ++r) {
          int m = m0 + wm + mt * 16 + quad * 4 + r;
          float val = (acc[mt][nt][r] + bval[nt]) * scale;
          int bb = m >> 11, s = m & 2047, h = n >> 6, hd = n & 63;
          Y[(((size_t)(bb * 8 + h) * 2048) + s) * 64 + hd] = f2bf(val);
        }
      }
  }
}

// ---------------------------------------------------------------- attention
// No-max softmax: sa = Q'.K (Q' prescaled by log2e/8); p = bit ? exp2(sa) : 0.
// l = row-sum via MFMA(P, ones) — lands in C-layout, no shuffles.
__global__ __launch_bounds__(256) void attn(
    const ushort* __restrict__ Qh, const ushort* __restrict__ Kh,
    const ushort* __restrict__ Vt, const unsigned long long* __restrict__ MB,
    ushort* __restrict__ O) {
  __shared__ ushort Ks[128 * 64];
  __shared__ ushort Vs[64 * 128];
  __shared__ ushort Ps[4][16 * 136];
  const int tid = threadIdx.x, wv = tid >> 6, l = tid & 63;
  const int quad = l >> 4, ln = l & 15;
  const int bh = blockIdx.x, qb = blockIdx.y;
  const int b = bh >> 3, h = bh & 7;
  const size_t hoff = (size_t)bh * 2048 * 64;
  const int q0 = qb * 64;
  const int qg = q0 + wv * 16 + ln;
  const int srK = l >> 3, scK = l & 7;
  const int srV = l >> 4, scV = l & 15;

  bf16x8 qf[2];
#pragma unroll
  for (int ks = 0; ks < 2; ++ks)
    qf[ks] = *(const bf16x8*)(Qh + hoff + (size_t)qg * 64 + ks * 32 + quad * 8);

  bf16x8 ones;
#pragma unroll
  for (int j = 0; j < 8; ++j) ones[j] = (__bf16)1.0f;

  f32x4 po[4] = {};
  f32x4 lacc = {};
  const unsigned long long* mrow = MB + ((size_t)b * 2048 + qg) * 32;

  for (int it = 0; it < 16; ++it) {
    const int kv0 = it * 128;
#pragma unroll
    for (int i = 0; i < 4; ++i) {
      int row = wv * 32 + i * 8 + srK;
      gll16(Kh + hoff + (size_t)(kv0 + row) * 64 + ((scK ^ (row & 7)) * 8),
            Ks + (wv * 32 + i * 8) * 64);
      int rowv = wv * 16 + i * 4 + srV;
      gll16(Vt + hoff + (size_t)rowv * 2048 + kv0 + ((scV ^ (rowv & 7)) * 8),
            Vs + (wv * 16 + i * 4) * 128);
    }
    unsigned long long mb0 = mrow[it * 2], mb1 = mrow[it * 2 + 1];
    __syncthreads();

    // S^T tiles: per mt, kv-rows mt*16+quad*4+{0..3}, q-col = ln
#pragma unroll
    for (int mt = 0; mt < 8; ++mt) {
      int row = mt * 16 + ln;
      bf16x8 a0 = *(const bf16x8*)&Ks[row * 64 + ((quad ^ (row & 7)) * 8)];
      bf16x8 a1 = *(const bf16x8*)&Ks[row * 64 + (((4 + quad) ^ (row & 7)) * 8)];
      f32x4 s4 = {};
      s4 = MFMA16(a0, qf[0], s4);
      s4 = MFMA16(a1, qf[1], s4);
      unsigned bits =
          (unsigned)(((mt < 4) ? mb0 : mb1) >> ((mt * 16 + quad * 4) & 63)) & 0xFu;
      float p0 = (bits & 1u) ? exp2f(s4[0]) : 0.f;
      float p1 = (bits & 2u) ? exp2f(s4[1]) : 0.f;
      float p2 = (bits & 4u) ? exp2f(s4[2]) : 0.f;
      float p3 = (bits & 8u) ? exp2f(s4[3]) : 0.f;
      ushort4 pk = { f2bf(p0), f2bf(p1), f2bf(p2), f2bf(p3) };
      *(ushort4*)&Ps[wv][ln * 136 + mt * 16 + quad * 4] = pk;
    }

    // PV + row-sum
#pragma unroll
    for (int ks = 0; ks < 4; ++ks) {
      bf16x8 ap = *(const bf16x8*)&Ps[wv][ln * 136 + ks * 32 + quad * 8];
      lacc = MFMA16(ap, ones, lacc);
#pragma unroll
      for (int ht = 0; ht < 4; ++ht) {
        int row = ht * 16 + ln;
        bf16x8 bv2 = *(const bf16x8*)&Vs[row * 128 + (((ks * 4 + quad) ^ (row & 7)) * 8)];
        po[ht] = MFMA16(ap, bv2, po[ht]);
      }
    }
    __syncthreads();
  }

#pragma unroll
  for (int r = 0; r < 4; ++r) {
    float linv = 1.0f / lacc[r];          // l for q-row quad*4+r (all cols equal)
    int s = q0 + wv * 16 + quad * 4 + r;
#pragma unroll
    for (int ht = 0; ht < 4; ++ht)
      O[((size_t)(b * 2048 + s)) * 512 + h * 64 + ht * 16 + ln] =
          f2bf(po[ht][r] * linv);
  }
}

// ---------------------------------------------------------------- out proj
// out[8192][512] f32 = Oh bf16 [m][k] * Wo bf16 [n][k] + bo
__global__ __launch_bounds__(256) void out_gemm(
    const ushort* __restrict__ X, const ushort* __restrict__ W,
    const float* __restrict__ bias, float* __restrict__ Y) {
  __shared__ ushort As[64 * 64];
  __shared__ ushort Ws[128 * 64];
  const int tid = threadIdx.x, wv = tid >> 6, l = tid & 63;
  const int quad = l >> 4, ln = l & 15;
  const int m0 = blockIdx.x * 64, n0 = blockIdx.y * 128;
  const int wm = (wv & 1) * 32, wn = (wv >> 1) * 64;
  const int sr = l >> 3, sc = l & 7;
  f32x4 acc[2][4] = {};
  for (int kk = 0; kk < 512; kk += 64) {
#pragma unroll
    for (int i = 0; i < 2; ++i) {
      int row = wv * 16 + i * 8 + sr;
      gll16(X + (size_t)(m0 + row) * 512 + kk + ((sc ^ (row & 7)) * 8),
            As + (wv * 16 + i * 8) * 64);
    }
#pragma unroll
    for (int i = 0; i < 4; ++i) {
      int row = wv * 32 + i * 8 + sr;
      gll16(W + (size_t)(n0 + row) * 512 + kk + ((sc ^ (row & 7)) * 8),
            Ws + (wv * 32 + i * 8) * 64);
    }
    __syncthreads();
#pragma unroll
    for (int ks = 0; ks < 2; ++ks) {
      bf16x8 a[2], bw[4];
#pragma unroll
      for (int mt = 0; mt < 2; ++mt) {
        int row = wm + mt * 16 + ln;
        a[mt] = *(const bf16x8*)&As[row * 64 + (((ks * 4 + quad) ^ (row & 7)) * 8)];
      }
#pragma unroll
      for (int nt = 0; nt < 4; ++nt) {
        int row = wn + nt * 16 + ln;
        bw[nt] = *(const bf16x8*)&Ws[row * 64 + (((ks * 4 + quad) ^ (row & 7)) * 8)];
      }
#pragma unroll
      for (int mt = 0; mt < 2; ++mt)
#pragma unroll
        for (int nt = 0; nt < 4; ++nt)
          acc[mt][nt] = MFMA16(a[mt], bw[nt], acc[mt][nt]);
    }
    __syncthreads();
  }
#pragma unroll
  for (int mt = 0; mt < 2; ++mt)
#pragma unroll
    for (int nt = 0; nt < 4; ++nt) {
      int n = n0 + wn + nt * 16 + ln;
      float bval = bias[n];
#pragma unroll
      for (int r = 0; r < 4; ++r) {
        int m = m0 + wm + mt * 16 + quad * 4 + r;
        Y[(size_t)m * 512 + n] = acc[mt][nt][r] + bval;
      }
    }
}

// ---------------------------------------------------------------- launch
extern "C" void kernel_launch(void* const* d_in, const int* in_sizes, int n_in,
                              void* d_out, int out_size, void* d_ws, size_t ws_size,
                              hipStream_t stream) {
  const float* q    = (const float*)d_in[0];
  const float* k    = (const float*)d_in[1];
  const float* v    = (const float*)d_in[2];
  const int*   mask = (const int*)d_in[3];
  const float* Wq   = (const float*)d_in[4];
  const float* bq   = (const float*)d_in[5];
  const float* Wk   = (const float*)d_in[6];
  const float* bk   = (const float*)d_in[7];
  const float* Wv   = (const float*)d_in[8];
  const float* bv   = (const float*)d_in[9];
  const float* Wo   = (const float*)d_in[10];
  const float* bo   = (const float*)d_in[11];
  float* out = (float*)d_out;

  uint8_t* ws = (uint8_t*)d_ws;
  const size_t MiB = 1u << 20;
  ushort* Ab = (ushort*)(ws + 0 * MiB);
  ushort* Qh = (ushort*)(ws + 8 * MiB);
  ushort* Kh = (ushort*)(ws + 16 * MiB);
  ushort* Vt = (ushort*)(ws + 24 * MiB);
  unsigned long long* MB = (unsigned long long*)(ws + 32 * MiB);
  ushort* Wb = (ushort*)(ws + 34 * MiB);   // Wq|Wk|Wv|Wo bf16, 512 KiB each

  cvt_w<<<dim3(64, 4), 256, 0, stream>>>(Wq, Wk, Wv, Wo, Wb);
  mask_bits_kernel<<<1024, 256, 0, stream>>>(mask, MB);
  qkv_gemm<<<dim3(128, 4, 3), 256, 0, stream>>>(q, k, v, Wb, bq, bk, bv, Qh, Kh, Vt);
  attn<<<dim3(32, 32), 256, 0, stream>>>(Qh, Kh, Vt, MB, Ab);
  out_gemm<<<dim3(128, 4), 256, 0, stream>>>(Ab, Wb + 3 * 262144, bo, out);
}

// Round 4
// 285.706 us; speedup vs baseline: 1.9199x; 1.0202x over previous
//
#include <hip/hip_runtime.h>
#include <cstdint>

// B=4, S=2048, H=512, NH=8, HD=64 — 10 launches:
//   cvt_w | mask_bits | (cvt_bf16 ; gemm_bt16<0|1>) x3 | attn(32x32 MFMA) | gemm_bt16<2>
// ws: Xb/Oh 0-8Mi | Qh 8-16 | Kh 16-24 | Vt 24-32 | MB 32-34 | Wb 34-36 MiB

typedef __bf16 bf16x8 __attribute__((ext_vector_type(8)));
typedef float  f32x4  __attribute__((ext_vector_type(4)));
typedef float  f32x16 __attribute__((ext_vector_type(16)));

#define MFMA16(a, b, c) __builtin_amdgcn_mfma_f32_16x16x32_bf16(a, b, c, 0, 0, 0)
#define MFMA32(a, b, c) __builtin_amdgcn_mfma_f32_32x32x16_bf16(a, b, c, 0, 0, 0)

__device__ __forceinline__ ushort f2bf(float f) {
  union { __bf16 h; ushort u; } v; v.h = (__bf16)f; return v.u;
}

typedef const __attribute__((address_space(1))) unsigned int* gas_u32;
typedef __attribute__((address_space(3))) unsigned int* las_u32;
__device__ __forceinline__ void gll16(const void* g, void* l) {
  __builtin_amdgcn_global_load_lds((gas_u32)g, (las_u32)l, 16, 0, 0);
}

// ---------------------------------------------------------------- fp32 -> bf16
__global__ __launch_bounds__(256) void cvt_bf16(
    const float* __restrict__ src, ushort* __restrict__ dst, int n4) {
  int i = blockIdx.x * 256 + threadIdx.x;
  int stride = gridDim.x * 256;
  for (; i < n4; i += stride) {
    float4 v = ((const float4*)src)[i];
    ushort4 o = { f2bf(v.x), f2bf(v.y), f2bf(v.z), f2bf(v.w) };
    ((ushort4*)dst)[i] = o;
  }
}

// ---------------------------------------------------------------- weights cvt
__global__ __launch_bounds__(256) void cvt_w(
    const float* __restrict__ w0, const float* __restrict__ w1,
    const float* __restrict__ w2, const float* __restrict__ w3,
    ushort* __restrict__ dst) {
  const float* src = (blockIdx.y == 0) ? w0 : (blockIdx.y == 1) ? w1
                   : (blockIdx.y == 2) ? w2 : w3;
  ushort* d = dst + (size_t)blockIdx.y * 262144;
  int i = blockIdx.x * 256 + threadIdx.x;
  for (int j = i; j < 65536; j += 16384) {
    float4 v = ((const float4*)src)[j];
    ushort4 o = { f2bf(v.x), f2bf(v.y), f2bf(v.z), f2bf(v.w) };
    ((ushort4*)d)[j] = o;
  }
}

// ---------------------------------------------------------------- mask bits
__global__ __launch_bounds__(256) void mask_bits_kernel(
    const int* __restrict__ mask, unsigned long long* __restrict__ MB) {
  const int lane = threadIdx.x & 63;
  const int wv = (int)((blockIdx.x * 256 + threadIdx.x) >> 6);
  const size_t base = (size_t)wv * 64;
  for (int j = 0; j < 64; j += 4) {
    int v0 = mask[(base + j + 0) * 64 + lane];
    int v1 = mask[(base + j + 1) * 64 + lane];
    int v2 = mask[(base + j + 2) * 64 + lane];
    int v3 = mask[(base + j + 3) * 64 + lane];
    unsigned long long b0 = __ballot(v0 != 0), b1 = __ballot(v1 != 0);
    unsigned long long b2 = __ballot(v2 != 0), b3 = __ballot(v3 != 0);
    if (lane == 0) {
      MB[base + j] = b0; MB[base + j + 1] = b1;
      MB[base + j + 2] = b2; MB[base + j + 3] = b3;
    }
  }
}

// ---------------------------------------------------------------- GEMM bt (bf16 in)
// Y[8192][512] = X bf16 [m][k] * W bf16 [n][k]; tile 64x128, BK=64.
// EPI 0: bf16 head-split [b][h][s][hd], (acc+bias)*scale
// EPI 1: bf16 head-split transposed [b][h][hd][s]
// EPI 2: fp32 [m][512] + bias
template <int EPI>
__global__ __launch_bounds__(256) void gemm_bt16(
    const ushort* __restrict__ X, const ushort* __restrict__ W,
    const float* __restrict__ bias, void* __restrict__ Y, float scale) {
  __shared__ ushort As[64 * 64];
  __shared__ ushort Ws[128 * 64];
  const int tid = threadIdx.x, wv = tid >> 6, l = tid & 63;
  const int quad = l >> 4, ln = l & 15;
  const int m0 = blockIdx.x * 64, n0 = blockIdx.y * 128;
  const int wm = (wv & 1) * 32, wn = (wv >> 1) * 64;
  const int sr = l >> 3, sc = l & 7;
  f32x4 acc[2][4] = {};
  for (int kk = 0; kk < 512; kk += 64) {
#pragma unroll
    for (int i = 0; i < 2; ++i) {
      int row = wv * 16 + i * 8 + sr;
      gll16(X + (size_t)(m0 + row) * 512 + kk + ((sc ^ (row & 7)) * 8),
            As + (wv * 16 + i * 8) * 64);
    }
#pragma unroll
    for (int i = 0; i < 4; ++i) {
      int row = wv * 32 + i * 8 + sr;
      gll16(W + (size_t)(n0 + row) * 512 + kk + ((sc ^ (row & 7)) * 8),
            Ws + (wv * 32 + i * 8) * 64);
    }
    __syncthreads();
#pragma unroll
    for (int ks = 0; ks < 2; ++ks) {
      bf16x8 a[2], bw[4];
#pragma unroll
      for (int mt = 0; mt < 2; ++mt) {
        int row = wm + mt * 16 + ln;
        a[mt] = *(const bf16x8*)&As[row * 64 + (((ks * 4 + quad) ^ (row & 7)) * 8)];
      }
#pragma unroll
      for (int nt = 0; nt < 4; ++nt) {
        int row = wn + nt * 16 + ln;
        bw[nt] = *(const bf16x8*)&Ws[row * 64 + (((ks * 4 + quad) ^ (row & 7)) * 8)];
      }
#pragma unroll
      for (int mt = 0; mt < 2; ++mt)
#pragma unroll
        for (int nt = 0; nt < 4; ++nt)
          acc[mt][nt] = MFMA16(a[mt], bw[nt], acc[mt][nt]);
    }
    __syncthreads();
  }
  float bval[4];
#pragma unroll
  for (int nt = 0; nt < 4; ++nt) bval[nt] = bias[n0 + wn + nt * 16 + ln];

  if constexpr (EPI == 1) {
#pragma unroll
    for (int nt = 0; nt < 4; ++nt) {
      int row = wn + nt * 16 + ln;
#pragma unroll
      for (int mt = 0; mt < 2; ++mt) {
        int mbase = wm + mt * 16 + quad * 4;
        ushort4 pk;
        pk.x = f2bf(acc[mt][nt][0] + bval[nt]);
        pk.y = f2bf(acc[mt][nt][1] + bval[nt]);
        pk.z = f2bf(acc[mt][nt][2] + bval[nt]);
        pk.w = f2bf(acc[mt][nt][3] + bval[nt]);
        int col = ((mbase >> 3) ^ (row & 7)) * 8 + ((mbase >> 2) & 1) * 4;
        *(ushort4*)&Ws[row * 64 + col] = pk;
      }
    }
    __syncthreads();
#pragma unroll
    for (int i = 0; i < 4; ++i) {
      int c = tid + i * 256;
      int row = c >> 3, cs = c & 7;
      int cl = cs ^ (row & 7);
      uint4 d = *(const uint4*)&Ws[row * 64 + cs * 8];
      int n = n0 + row, m = m0 + cl * 8;
      int bb = m >> 11, s = m & 2047, h = n >> 6, hd = n & 63;
      *(uint4*)((ushort*)Y + ((size_t)((bb * 8 + h) * 64 + hd)) * 2048 + s) = d;
    }
  } else {
#pragma unroll
    for (int mt = 0; mt < 2; ++mt)
#pragma unroll
      for (int nt = 0; nt < 4; ++nt) {
        int n = n0 + wn + nt * 16 + ln;
#pragma unroll
        for (int r = 0; r < 4; ++r) {
          int m = m0 + wm + mt * 16 + quad * 4 + r;
          float val = (acc[mt][nt][r] + bval[nt]) * scale;
          if constexpr (EPI == 0) {
            int bb = m >> 11, s = m & 2047, h = n >> 6, hd = n & 63;
            ((ushort*)Y)[(((size_t)(bb * 8 + h) * 2048) + s) * 64 + hd] = f2bf(val);
          } else {
            ((float*)Y)[(size_t)m * 512 + n] = val;
          }
        }
      }
  }
}

// ---------------------------------------------------------------- attention
// 32x32x16 MFMA, S^T = K.Q^T; P^T -> PV B-frag via shfl_xor(32); no Ps LDS.
// grid (bh=32, qb=32), 4 waves: wave = (qh = wv>>1 selects 32 q, kvh = wv&1
// selects 64 of 128 kv per iter). End: cross-wave po/l merge via LDS.
__global__ __launch_bounds__(256, 4) void attn(
    const ushort* __restrict__ Qh, const ushort* __restrict__ Kh,
    const ushort* __restrict__ Vt, const unsigned long long* __restrict__ MB,
    ushort* __restrict__ O) {
  __shared__ ushort SMEM[16384];          // Ks 16KB | Vs 16KB (reused at end)
  ushort* Ks = SMEM;                      // [kv 128][d 64], chunk-swizzled
  ushort* Vs = SMEM + 8192;               // [hd 64][kv 128], chunk-swizzled
  const int tid = threadIdx.x, wv = tid >> 6, lane = tid & 63;
  const int hs = lane >> 5, lq = lane & 31;
  const int qh = wv >> 1, kvh = wv & 1;
  const int bh = blockIdx.x, qb = blockIdx.y;
  const size_t hoff = (size_t)bh * 2048 * 64;
  const int q0 = qb * 64;
  const int qg = q0 + qh * 32 + lq;       // lane's q
  const int srK = lane >> 3, scK = lane & 7;
  const int srV = lane >> 4, scV = lane & 15;

  bf16x8 qf[4];                            // B-frag: k = 16*ki + 8*hs + j
#pragma unroll
  for (int ki = 0; ki < 4; ++ki)
    qf[ki] = *(const bf16x8*)(Qh + hoff + (size_t)qg * 64 + ki * 16 + hs * 8);

  f32x16 po0 = {}, po1 = {};               // O^T: [hd-tile 0/1], col=q
  float l_own = 0.f;
  const unsigned long long* mrow = MB + ((size_t)(bh >> 3) * 2048 + qg) * 32;

  for (int it = 0; it < 16; ++it) {
    const int kv0 = it * 128;
#pragma unroll
    for (int i = 0; i < 4; ++i) {
      int row = wv * 32 + i * 8 + srK;     // K rows (kv)
      gll16(Kh + hoff + (size_t)(kv0 + row) * 64 + ((scK ^ (row & 7)) * 8),
            Ks + (wv * 32 + i * 8) * 64);
      int rv = wv * 16 + i * 4 + srV;      // V rows (hd)
      gll16(Vt + hoff + (size_t)rv * 2048 + kv0 + ((scV ^ (rv & 7)) * 8),
            Vs + (wv * 16 + i * 4) * 128);
    }
    unsigned long long mbw = mrow[it * 2 + kvh];
    __syncthreads();

#pragma unroll
    for (int ch = 0; ch < 2; ++ch) {       // two 32-kv chunks for this wave
      const int kvb = kvh * 64 + ch * 32;
      // S^T C-tile: rows kv (m), cols q (n=lane&31)
      f32x16 sc_ = {};
#pragma unroll
      for (int ki = 0; ki < 4; ++ki) {
        int row = kvb + lq;
        bf16x8 ak = *(const bf16x8*)&Ks[row * 64 + (((2 * ki + hs) ^ (row & 7)) * 8)];
        sc_ = MFMA32(ak, qf[ki], sc_);
      }
      // mask + exp2 + row-sum + pack; reg r=4c+b -> kv = 8c+4hs+b (in chunk)
      uint pk[8];
      float psum = 0.f;
#pragma unroll
      for (int c = 0; c < 4; ++c) {
        unsigned nib = (unsigned)(mbw >> (ch * 32 + c * 8 + hs * 4)) & 0xFu;
        float p0 = (nib & 1u) ? exp2f(sc_[4 * c + 0]) : 0.f;
        float p1 = (nib & 2u) ? exp2f(sc_[4 * c + 1]) : 0.f;
        float p2 = (nib & 4u) ? exp2f(sc_[4 * c + 2]) : 0.f;
        float p3 = (nib & 8u) ? exp2f(sc_[4 * c + 3]) : 0.f;
        psum += (p0 + p1) + (p2 + p3);
        pk[2 * c + 0] = (uint)f2bf(p0) | ((uint)f2bf(p1) << 16);
        pk[2 * c + 1] = (uint)f2bf(p2) | ((uint)f2bf(p3) << 16);
      }
      l_own += psum;
      // exchange across lane^32: B[t][j2<2] from half0's c=2t+hs_d, j2>=2 from half1's
      uint bx[4];
#pragma unroll
      for (int t2 = 0; t2 < 2; ++t2)
#pragma unroll
        for (int b2 = 0; b2 < 2; ++b2) {
          uint snd = hs ? pk[4 * t2 + b2] : pk[4 * t2 + 2 + b2];
          bx[t2 * 2 + b2] = (uint)__shfl_xor((int)snd, 32);
        }
#pragma unroll
      for (int t2 = 0; t2 < 2; ++t2) {
        union { uint u[4]; bf16x8 v; } bp;
        bp.u[0] = hs ? bx[2 * t2 + 0] : pk[4 * t2 + 0];
        bp.u[1] = hs ? bx[2 * t2 + 1] : pk[4 * t2 + 1];
        bp.u[2] = hs ? pk[4 * t2 + 2] : bx[2 * t2 + 0];
        bp.u[3] = hs ? pk[4 * t2 + 3] : bx[2 * t2 + 1];
        // PV: A = V^T[hd][kv], k-chunk = kvb + 16*t2 + 8*hs
#pragma unroll
        for (int m2 = 0; m2 < 2; ++m2) {
          int hd = m2 * 32 + lq;
          int gch = (kvb >> 3) + 2 * t2 + hs;   // global 8-kv chunk 0..15
          bf16x8 av = *(const bf16x8*)&Vs[hd * 128 + ((gch ^ (hd & 7)) * 8)];
          if (m2 == 0) po0 = MFMA32(av, bp.v, po0);
          else         po1 = MFMA32(av, bp.v, po1);
        }
      }
    }
    __syncthreads();
  }

  // ---- merge kv-halves + epilogue
  l_own += __shfl_xor(l_own, 32);          // full l over this wave's kv half
  float* psh = (float*)Ks;                 // [qh][32][64] f32 = 16 KB
  float* lsh = (float*)Vs;                 // [qh][64]
  ushort* Osh = Vs + 256;                  // [64 q][72] ushorts = 9216 B
  if (kvh == 1) {
#pragma unroll
    for (int i = 0; i < 16; ++i) psh[(qh * 32 + i) * 64 + lane] = po0[i];
#pragma unroll
    for (int i = 0; i < 16; ++i) psh[(qh * 32 + 16 + i) * 64 + lane] = po1[i];
    lsh[qh * 64 + lane] = l_own;
  }
  __syncthreads();
  if (kvh == 0) {
    float linv = 1.0f / (l_own + lsh[qh * 64 + lane]);
    int row = qh * 32 + lq;
#pragma unroll
    for (int m2 = 0; m2 < 2; ++m2) {
#pragma unroll
      for (int c = 0; c < 4; ++c)
#pragma unroll
        for (int b2 = 0; b2 < 2; ++b2) {
          int r = 4 * c + 2 * b2;
          float v0, v1;
          if (m2 == 0) {
            v0 = (po0[r] + psh[(qh * 32 + r) * 64 + lane]) * linv;
            v1 = (po0[r + 1] + psh[(qh * 32 + r + 1) * 64 + lane]) * linv;
          } else {
            v0 = (po1[r] + psh[(qh * 32 + 16 + r) * 64 + lane]) * linv;
            v1 = (po1[r + 1] + psh[(qh * 32 + 16 + r + 1) * 64 + lane]) * linv;
          }
          int hd = m2 * 32 + 8 * c + 4 * hs + 2 * b2;
          *(uint*)&Osh[row * 72 + hd] = (uint)f2bf(v0) | ((uint)f2bf(v1) << 16);
        }
    }
  }
  __syncthreads();
  for (int i = tid; i < 512; i += 256) {   // 64 rows x 4 uint4
    int row = i >> 3, cc = i & 7;
    uint4 d = *(const uint4*)&Osh[row * 72 + cc * 8];
    *(uint4*)(O + ((size_t)((bh >> 3) * 2048 + q0 + row)) * 512 +
              (bh & 7) * 64 + cc * 8) = d;
  }
}

// ---------------------------------------------------------------- launch
extern "C" void kernel_launch(void* const* d_in, const int* in_sizes, int n_in,
                              void* d_out, int out_size, void* d_ws, size_t ws_size,
                              hipStream_t stream) {
  const float* q    = (const float*)d_in[0];
  const float* k    = (const float*)d_in[1];
  const float* v    = (const float*)d_in[2];
  const int*   mask = (const int*)d_in[3];
  const float* Wq   = (const float*)d_in[4];
  const float* bq   = (const float*)d_in[5];
  const float* Wk   = (const float*)d_in[6];
  const float* bk   = (const float*)d_in[7];
  const float* Wv   = (const float*)d_in[8];
  const float* bv   = (const float*)d_in[9];
  const float* Wo   = (const float*)d_in[10];
  const float* bo   = (const float*)d_in[11];
  float* out = (float*)d_out;

  uint8_t* ws = (uint8_t*)d_ws;
  const size_t MiB = 1u << 20;
  ushort* Xb = (ushort*)(ws + 0 * MiB);    // staged bf16 input / later Oh
  ushort* Qh = (ushort*)(ws + 8 * MiB);
  ushort* Kh = (ushort*)(ws + 16 * MiB);
  ushort* Vt = (ushort*)(ws + 24 * MiB);
  unsigned long long* MB = (unsigned long long*)(ws + 32 * MiB);
  ushort* Wb = (ushort*)(ws + 34 * MiB);

  cvt_w<<<dim3(64, 4), 256, 0, stream>>>(Wq, Wk, Wv, Wo, Wb);
  mask_bits_kernel<<<1024, 256, 0, stream>>>(mask, MB);

  cvt_bf16<<<1024, 256, 0, stream>>>(q, Xb, 1048576);
  gemm_bt16<0><<<dim3(128, 4), 256, 0, stream>>>(Xb, Wb, bq, Qh, 0.18033688011112042f);
  cvt_bf16<<<1024, 256, 0, stream>>>(k, Xb, 1048576);
  gemm_bt16<0><<<dim3(128, 4), 256, 0, stream>>>(Xb, Wb + 262144, bk, Kh, 1.0f);
  cvt_bf16<<<1024, 256, 0, stream>>>(v, Xb, 1048576);
  gemm_bt16<1><<<dim3(128, 4), 256, 0, stream>>>(Xb, Wb + 2 * 262144, bv, Vt, 1.0f);

  attn<<<dim3(32, 32), 256, 0, stream>>>(Qh, Kh, Vt, MB, Xb);
  gemm_bt16<2><<<dim3(128, 4), 256, 0, stream>>>(Xb, Wb + 3 * 262144, bo, out, 1.0f);
}